// Round 1
// baseline (1365.983 us; speedup 1.0000x reference)
//
#include <hip/hip_runtime.h>
#include <math.h>

#define TT   256   // timesteps
#define HH   64    // hidden
#define G4   256   // 4*H gate columns
#define INw  46    // input size
#define NCLS 8     // classes
#define BT   4     // batch rows per scan block
#define ST   64    // staged timesteps per chunk
#define B2   8     // batch rows per epilogue block

__device__ __forceinline__ float frcp(float x) { return __builtin_amdgcn_rcpf(x); }
__device__ __forceinline__ float sigmoid_f(float x) { return frcp(1.f + __expf(-x)); }
__device__ __forceinline__ float tanh_f(float x) {
    float a = fabsf(x);
    float e = __expf(-2.f * a);
    float r = (1.f - e) * frcp(1.f + e);
    return x >= 0.f ? r : -r;
}
__device__ __forceinline__ float dot4(float4 w, float4 a, float acc) {
    acc = fmaf(w.x, a.x, acc);
    acc = fmaf(w.y, a.y, acc);
    acc = fmaf(w.z, a.z, acc);
    acc = fmaf(w.w, a.w, acc);
    return acc;
}

// Forward LSTM scan. One block = 4 batch rows, 256 threads (thread j = gate col j).
__global__ __launch_bounds__(256, 2) void lstm_fwd_scan(
    const float* __restrict__ x,     // (B,T,46)
    const float* __restrict__ Wih,   // (256,46)
    const float* __restrict__ Whh,   // (256,64)
    const float* __restrict__ bih,   // (256)
    const float* __restrict__ bhh,   // (256)
    float* __restrict__ hf_out)      // (B,64)
{
    __shared__ float x_lds[BT][ST][48];  // padded 46->48 for aligned float4
    __shared__ float h_lds[BT][HH];
    __shared__ float act[BT][G4];

    const int j  = threadIdx.x;
    const int b0 = blockIdx.x * BT;
    const int bb = j >> 6;     // this thread's owned (batch,unit) pair
    const int l  = j & 63;

    // weights for gate column j in registers (compile-time-indexed float4 arrays)
    float4 wih4[12];
#pragma unroll
    for (int ii = 0; ii < 11; ++ii)
        wih4[ii] = make_float4(Wih[j*INw + 4*ii + 0], Wih[j*INw + 4*ii + 1],
                               Wih[j*INw + 4*ii + 2], Wih[j*INw + 4*ii + 3]);
    wih4[11] = make_float4(Wih[j*INw + 44], Wih[j*INw + 45], 0.f, 0.f);

    float4 whh4[16];
#pragma unroll
    for (int ii = 0; ii < 16; ++ii)
        whh4[ii] = make_float4(Whh[j*HH + 4*ii + 0], Whh[j*HH + 4*ii + 1],
                               Whh[j*HH + 4*ii + 2], Whh[j*HH + 4*ii + 3]);

    const float bias = bih[j] + bhh[j];
    const bool  gate_is_tanh = (bb == 2);  // wave-uniform: wave 2 = g-gate

    h_lds[bb][l] = 0.f;
    float c = 0.f, hcur = 0.f;

    for (int t0 = 0; t0 < TT; t0 += ST) {
        // ---- stage x chunk (previous inner loop ended with a barrier) ----
        const float* xsrc = x + (size_t)b0 * TT * INw + (size_t)t0 * INw;
        for (int e = j; e < BT * ST * INw; e += 256) {
            int b = e / (ST * INw);
            int r = e - b * (ST * INw);
            int t = r / INw;
            int i = r - t * INw;
            x_lds[b][t][i] = xsrc[(size_t)b * TT * INw + r];
        }
        for (int e = j; e < BT * ST; e += 256) {
            int b = e >> 6, t = e & 63;
            x_lds[b][t][46] = 0.f;
            x_lds[b][t][47] = 0.f;
        }
        __syncthreads();

        for (int ts = 0; ts < ST; ++ts) {
            float acc[BT];
#pragma unroll
            for (int b = 0; b < BT; ++b) acc[b] = bias;

            // input projection (broadcast LDS reads, weights in regs)
#pragma unroll
            for (int ii = 0; ii < 12; ++ii) {
                float4 w = wih4[ii];
#pragma unroll
                for (int b = 0; b < BT; ++b) {
                    float4 a = *(const float4*)&x_lds[b][ts][4*ii];
                    acc[b] = dot4(w, a, acc[b]);
                }
            }
            // recurrent projection
#pragma unroll
            for (int ii = 0; ii < 16; ++ii) {
                float4 w = whh4[ii];
#pragma unroll
                for (int b = 0; b < BT; ++b) {
                    float4 a = *(const float4*)&h_lds[b][4*ii];
                    acc[b] = dot4(w, a, acc[b]);
                }
            }

            // gate nonlinearity (wave-uniform branch)
            float v[BT];
            if (gate_is_tanh) {
#pragma unroll
                for (int b = 0; b < BT; ++b) v[b] = tanh_f(acc[b]);
            } else {
#pragma unroll
                for (int b = 0; b < BT; ++b) v[b] = sigmoid_f(acc[b]);
            }
#pragma unroll
            for (int b = 0; b < BT; ++b) act[b][j] = v[b];
            __syncthreads();

            // cell/hidden update: thread owns (bb, l)
            float ig = act[bb][l];
            float fg = act[bb][64  + l];
            float gg = act[bb][128 + l];
            float og = act[bb][192 + l];
            c    = fmaf(fg, c, ig * gg);
            hcur = og * tanh_f(c);
            h_lds[bb][l] = hcur;
            __syncthreads();
        }
    }
    hf_out[(size_t)(b0 + bb) * HH + l] = hcur;
}

// Backward direction = ONE LSTM step on x[:,T-1,:] from zero state (Whh_b unused),
// then FC + softmax.
__global__ __launch_bounds__(256) void lstm_bwd_fc(
    const float* __restrict__ x,
    const float* __restrict__ Wih,   // backward Wih (256,46)
    const float* __restrict__ bih,
    const float* __restrict__ bhh,
    const float* __restrict__ fcW,   // (8,128)
    const float* __restrict__ fcb,   // (8)
    const float* __restrict__ hf,    // (B,64) forward final hidden
    float* __restrict__ out)         // (B,8)
{
    __shared__ float xl[B2][48];
    __shared__ float act[B2][G4];
    __shared__ float hbl[B2][HH];

    const int j  = threadIdx.x;
    const int b0 = blockIdx.x * B2;

    for (int e = j; e < B2 * INw; e += 256) {
        int b = e / INw, i = e - b * INw;
        xl[b][i] = x[((size_t)(b0 + b) * TT + (TT - 1)) * INw + i];
    }
    if (j < B2) { xl[j][46] = 0.f; xl[j][47] = 0.f; }
    __syncthreads();

    float4 wih4[12];
#pragma unroll
    for (int ii = 0; ii < 11; ++ii)
        wih4[ii] = make_float4(Wih[j*INw + 4*ii + 0], Wih[j*INw + 4*ii + 1],
                               Wih[j*INw + 4*ii + 2], Wih[j*INw + 4*ii + 3]);
    wih4[11] = make_float4(Wih[j*INw + 44], Wih[j*INw + 45], 0.f, 0.f);
    const float bias = bih[j] + bhh[j];
    const bool  gate_is_tanh = ((j >> 6) == 2);

#pragma unroll
    for (int b = 0; b < B2; ++b) {
        float a = bias;
#pragma unroll
        for (int ii = 0; ii < 12; ++ii) {
            float4 w  = wih4[ii];
            float4 xv = *(const float4*)&xl[b][4*ii];
            a = dot4(w, xv, a);
        }
        act[b][j] = gate_is_tanh ? tanh_f(a) : sigmoid_f(a);
    }
    __syncthreads();

    // h_b = o * tanh(i*g)   (c0 = 0 so f*c vanishes)
    for (int p = j; p < B2 * HH; p += 256) {
        int b = p >> 6, l = p & 63;
        float ig = act[b][l];
        float gg = act[b][128 + l];
        float og = act[b][192 + l];
        hbl[b][l] = og * tanh_f(ig * gg);
    }
    __syncthreads();

    // FC + softmax: 64 threads, one logit each (b = j/8, class n = j%8)
    if (j < B2 * NCLS) {
        int b = j >> 3, n = j & 7;
        float a = fcb[n];
        const float* hfr = hf + (size_t)(b0 + b) * HH;
#pragma unroll
        for (int l = 0; l < HH; ++l) {
            a = fmaf(fcW[n * 2 * HH + l],      hfr[l],    a);
            a = fmaf(fcW[n * 2 * HH + HH + l], hbl[b][l], a);
        }
        float m = a;
        m = fmaxf(m, __shfl_xor(m, 1, 8));
        m = fmaxf(m, __shfl_xor(m, 2, 8));
        m = fmaxf(m, __shfl_xor(m, 4, 8));
        float e = __expf(a - m);
        float s = e;
        s += __shfl_xor(s, 1, 8);
        s += __shfl_xor(s, 2, 8);
        s += __shfl_xor(s, 4, 8);
        out[(size_t)(b0 + b) * NCLS + n] = e / s;
    }
}

extern "C" void kernel_launch(void* const* d_in, const int* in_sizes, int n_in,
                              void* d_out, int out_size, void* d_ws, size_t ws_size,
                              hipStream_t stream) {
    const float* x     = (const float*)d_in[0];
    const float* Wih_f = (const float*)d_in[1];
    const float* Whh_f = (const float*)d_in[2];
    const float* bih_f = (const float*)d_in[3];
    const float* bhh_f = (const float*)d_in[4];
    const float* Wih_b = (const float*)d_in[5];
    // d_in[6] = Whh_b: unused — backward contributes only its first step (h0 = 0)
    const float* bih_b = (const float*)d_in[7];
    const float* bhh_b = (const float*)d_in[8];
    const float* fcW   = (const float*)d_in[9];
    const float* fcb   = (const float*)d_in[10];
    float* out = (float*)d_out;
    float* hf  = (float*)d_ws;   // 2048*64 fp32 = 512 KB scratch

    hipLaunchKernelGGL(lstm_fwd_scan, dim3(2048 / BT), dim3(256), 0, stream,
                       x, Wih_f, Whh_f, bih_f, bhh_f, hf);
    hipLaunchKernelGGL(lstm_bwd_fc, dim3(2048 / B2), dim3(256), 0, stream,
                       x, Wih_b, bih_b, bhh_b, fcW, fcb, hf, out);
}

// Round 2
// 1363.157 us; speedup vs baseline: 1.0021x; 1.0021x over previous
//
#include <hip/hip_runtime.h>
#include <math.h>

#define TT   256   // timesteps
#define HH   64    // hidden
#define G4   256   // 4*H gate columns
#define INw  46    // input size
#define NCLS 8     // classes
#define BT   4     // batch rows per scan block (fallback kernel)
#define BT2  2     // batch rows per scan block (xp kernel)
#define ST   64    // staged timesteps per chunk (fallback kernel)
#define B2   8     // batch rows per epilogue block
#define RPB  128   // rows per block in xp gemm
#define RC   64    // rows per LDS chunk in xp gemm

__device__ __forceinline__ float frcp(float x) { return __builtin_amdgcn_rcpf(x); }
__device__ __forceinline__ float sigmoid_f(float x) { return frcp(1.f + __expf(-x)); }
__device__ __forceinline__ float tanh_f(float x) {
    float a = fabsf(x);
    float e = __expf(-2.f * a);
    float r = (1.f - e) * frcp(1.f + e);
    return x >= 0.f ? r : -r;
}
__device__ __forceinline__ float dot4(float4 w, float4 a, float acc) {
    acc = fmaf(w.x, a.x, acc);
    acc = fmaf(w.y, a.y, acc);
    acc = fmaf(w.z, a.z, acc);
    acc = fmaf(w.w, a.w, acc);
    return acc;
}

// ---------------------------------------------------------------------------
// Kernel A: input projection xp[r][j] = x[r]·Wih[j] + bih[j] + bhh[j]
// for all r in B*T. Fully parallel fp32 GEMM (no fp32 MFMA on CDNA4).
// ---------------------------------------------------------------------------
__global__ __launch_bounds__(256, 4) void xp_gemm(
    const float* __restrict__ x,     // (B*T, 46)
    const float* __restrict__ Wih,   // (256,46)
    const float* __restrict__ bih,
    const float* __restrict__ bhh,
    float* __restrict__ xp)          // (B*T, 256)
{
    __shared__ float xl[RC][48];
    const int j = threadIdx.x;
    const size_t r0 = (size_t)blockIdx.x * RPB;

    float4 w[12];
#pragma unroll
    for (int ii = 0; ii < 11; ++ii)
        w[ii] = make_float4(Wih[j*INw + 4*ii + 0], Wih[j*INw + 4*ii + 1],
                            Wih[j*INw + 4*ii + 2], Wih[j*INw + 4*ii + 3]);
    w[11] = make_float4(Wih[j*INw + 44], Wih[j*INw + 45], 0.f, 0.f);
    const float bias = bih[j] + bhh[j];

    for (int ch = 0; ch < RPB / RC; ++ch) {
        const size_t rbase = r0 + (size_t)ch * RC;
        for (int e = j; e < RC * INw; e += 256) {
            int r = e / INw, i = e - r * INw;
            xl[r][i] = x[rbase * INw + e];
        }
        for (int e = j; e < RC; e += 256) { xl[e][46] = 0.f; xl[e][47] = 0.f; }
        __syncthreads();

        for (int r = 0; r < RC; ++r) {
            float a = bias;
#pragma unroll
            for (int ii = 0; ii < 12; ++ii) {
                float4 xv = *(const float4*)&xl[r][4*ii];
                a = dot4(w[ii], xv, a);
            }
            xp[(rbase + r) * G4 + j] = a;
        }
        __syncthreads();
    }
}

// ---------------------------------------------------------------------------
// Kernel B: recurrent-only scan. Thread j = gate column j, BT2=2 batch rows.
// xp streamed from global (coalesced, register-prefetched). 2 barriers/step.
// ---------------------------------------------------------------------------
__global__ __launch_bounds__(256, 4) void lstm_scan_xp(
    const float* __restrict__ xp,    // (B,T,256)
    const float* __restrict__ Whh,   // (256,64)
    float* __restrict__ hf_out)      // (B,64)
{
    __shared__ float h_lds[BT2][HH];
    __shared__ float act[BT2][G4];

    const int j  = threadIdx.x;
    const int b0 = blockIdx.x * BT2;
    const int p  = j >> 6;
    const int l  = j & 63;

    float4 whh4[16];
#pragma unroll
    for (int ii = 0; ii < 16; ++ii)
        whh4[ii] = make_float4(Whh[j*HH + 4*ii + 0], Whh[j*HH + 4*ii + 1],
                               Whh[j*HH + 4*ii + 2], Whh[j*HH + 4*ii + 3]);
    const bool gate_is_tanh = (p == 2);   // wave-uniform

    if (p < BT2) h_lds[p][l] = 0.f;
    float c = 0.f, h = 0.f;

    const float* xp0 = xp + ((size_t)b0 * TT) * G4 + j;
    const float* xp1 = xp + ((size_t)(b0 + 1) * TT) * G4 + j;
    float xc0 = xp0[0];
    float xc1 = xp1[0];
    __syncthreads();

    for (int t = 0; t < TT; ++t) {
        const int tn = (t + 1 < TT) ? t + 1 : TT - 1;
        float xn0 = xp0[(size_t)tn * G4];   // prefetch next step's xp
        float xn1 = xp1[(size_t)tn * G4];

        float a0 = xc0, a1 = xc1;
#pragma unroll
        for (int ii = 0; ii < 16; ++ii) {
            float4 w  = whh4[ii];
            float4 h0 = *(const float4*)&h_lds[0][4*ii];
            float4 h1 = *(const float4*)&h_lds[1][4*ii];
            a0 = dot4(w, h0, a0);
            a1 = dot4(w, h1, a1);
        }
        float v0, v1;
        if (gate_is_tanh) { v0 = tanh_f(a0);    v1 = tanh_f(a1); }
        else              { v0 = sigmoid_f(a0); v1 = sigmoid_f(a1); }
        act[0][j] = v0;
        act[1][j] = v1;
        __syncthreads();

        if (p < BT2) {
            float ig = act[p][l];
            float fg = act[p][64  + l];
            float gg = act[p][128 + l];
            float og = act[p][192 + l];
            c = fmaf(fg, c, ig * gg);
            h = og * tanh_f(c);
            h_lds[p][l] = h;
        }
        xc0 = xn0; xc1 = xn1;
        __syncthreads();
    }
    if (p < BT2) hf_out[(size_t)(b0 + p) * HH + l] = h;
}

// ---------------------------------------------------------------------------
// Fallback (round-1, known-correct): fused scan, BT=4 rows/block.
// Used only if ws_size can't hold the 512 MB xp buffer.
// ---------------------------------------------------------------------------
__global__ __launch_bounds__(256, 2) void lstm_fwd_scan(
    const float* __restrict__ x,
    const float* __restrict__ Wih,
    const float* __restrict__ Whh,
    const float* __restrict__ bih,
    const float* __restrict__ bhh,
    float* __restrict__ hf_out)
{
    __shared__ float x_lds[BT][ST][48];
    __shared__ float h_lds[BT][HH];
    __shared__ float act[BT][G4];

    const int j  = threadIdx.x;
    const int b0 = blockIdx.x * BT;
    const int bb = j >> 6;
    const int l  = j & 63;

    float4 wih4[12];
#pragma unroll
    for (int ii = 0; ii < 11; ++ii)
        wih4[ii] = make_float4(Wih[j*INw + 4*ii + 0], Wih[j*INw + 4*ii + 1],
                               Wih[j*INw + 4*ii + 2], Wih[j*INw + 4*ii + 3]);
    wih4[11] = make_float4(Wih[j*INw + 44], Wih[j*INw + 45], 0.f, 0.f);

    float4 whh4[16];
#pragma unroll
    for (int ii = 0; ii < 16; ++ii)
        whh4[ii] = make_float4(Whh[j*HH + 4*ii + 0], Whh[j*HH + 4*ii + 1],
                               Whh[j*HH + 4*ii + 2], Whh[j*HH + 4*ii + 3]);

    const float bias = bih[j] + bhh[j];
    const bool  gate_is_tanh = (bb == 2);

    h_lds[bb][l] = 0.f;
    float c = 0.f, hcur = 0.f;

    for (int t0 = 0; t0 < TT; t0 += ST) {
        const float* xsrc = x + (size_t)b0 * TT * INw + (size_t)t0 * INw;
        for (int e = j; e < BT * ST * INw; e += 256) {
            int b = e / (ST * INw);
            int r = e - b * (ST * INw);
            int t = r / INw;
            int i = r - t * INw;
            x_lds[b][t][i] = xsrc[(size_t)b * TT * INw + r];
        }
        for (int e = j; e < BT * ST; e += 256) {
            int b = e >> 6, t = e & 63;
            x_lds[b][t][46] = 0.f;
            x_lds[b][t][47] = 0.f;
        }
        __syncthreads();

        for (int ts = 0; ts < ST; ++ts) {
            float acc[BT];
#pragma unroll
            for (int b = 0; b < BT; ++b) acc[b] = bias;
#pragma unroll
            for (int ii = 0; ii < 12; ++ii) {
                float4 w = wih4[ii];
#pragma unroll
                for (int b = 0; b < BT; ++b) {
                    float4 a = *(const float4*)&x_lds[b][ts][4*ii];
                    acc[b] = dot4(w, a, acc[b]);
                }
            }
#pragma unroll
            for (int ii = 0; ii < 16; ++ii) {
                float4 w = whh4[ii];
#pragma unroll
                for (int b = 0; b < BT; ++b) {
                    float4 a = *(const float4*)&h_lds[b][4*ii];
                    acc[b] = dot4(w, a, acc[b]);
                }
            }
            float v[BT];
            if (gate_is_tanh) {
#pragma unroll
                for (int b = 0; b < BT; ++b) v[b] = tanh_f(acc[b]);
            } else {
#pragma unroll
                for (int b = 0; b < BT; ++b) v[b] = sigmoid_f(acc[b]);
            }
#pragma unroll
            for (int b = 0; b < BT; ++b) act[b][j] = v[b];
            __syncthreads();

            float ig = act[bb][l];
            float fg = act[bb][64  + l];
            float gg = act[bb][128 + l];
            float og = act[bb][192 + l];
            c    = fmaf(fg, c, ig * gg);
            hcur = og * tanh_f(c);
            h_lds[bb][l] = hcur;
            __syncthreads();
        }
    }
    hf_out[(size_t)(b0 + bb) * HH + l] = hcur;
}

// ---------------------------------------------------------------------------
// Epilogue: backward dir = ONE LSTM step on x[:,T-1,:] (h0=c0=0, Whh_b unused),
// then FC + softmax.
// ---------------------------------------------------------------------------
__global__ __launch_bounds__(256) void lstm_bwd_fc(
    const float* __restrict__ x,
    const float* __restrict__ Wih,
    const float* __restrict__ bih,
    const float* __restrict__ bhh,
    const float* __restrict__ fcW,
    const float* __restrict__ fcb,
    const float* __restrict__ hf,
    float* __restrict__ out)
{
    __shared__ float xl[B2][48];
    __shared__ float act[B2][G4];
    __shared__ float hbl[B2][HH];

    const int j  = threadIdx.x;
    const int b0 = blockIdx.x * B2;

    for (int e = j; e < B2 * INw; e += 256) {
        int b = e / INw, i = e - b * INw;
        xl[b][i] = x[((size_t)(b0 + b) * TT + (TT - 1)) * INw + i];
    }
    if (j < B2) { xl[j][46] = 0.f; xl[j][47] = 0.f; }
    __syncthreads();

    float4 wih4[12];
#pragma unroll
    for (int ii = 0; ii < 11; ++ii)
        wih4[ii] = make_float4(Wih[j*INw + 4*ii + 0], Wih[j*INw + 4*ii + 1],
                               Wih[j*INw + 4*ii + 2], Wih[j*INw + 4*ii + 3]);
    wih4[11] = make_float4(Wih[j*INw + 44], Wih[j*INw + 45], 0.f, 0.f);
    const float bias = bih[j] + bhh[j];
    const bool  gate_is_tanh = ((j >> 6) == 2);

#pragma unroll
    for (int b = 0; b < B2; ++b) {
        float a = bias;
#pragma unroll
        for (int ii = 0; ii < 12; ++ii) {
            float4 xv = *(const float4*)&xl[b][4*ii];
            a = dot4(wih4[ii], xv, a);
        }
        act[b][j] = gate_is_tanh ? tanh_f(a) : sigmoid_f(a);
    }
    __syncthreads();

    for (int ppp = j; ppp < B2 * HH; ppp += 256) {
        int b = ppp >> 6, l = ppp & 63;
        float ig = act[b][l];
        float gg = act[b][128 + l];
        float og = act[b][192 + l];
        hbl[b][l] = og * tanh_f(ig * gg);
    }
    __syncthreads();

    if (j < B2 * NCLS) {
        int b = j >> 3, n = j & 7;
        float a = fcb[n];
        const float* hfr = hf + (size_t)(b0 + b) * HH;
#pragma unroll
        for (int l = 0; l < HH; ++l) {
            a = fmaf(fcW[n * 2 * HH + l],      hfr[l],    a);
            a = fmaf(fcW[n * 2 * HH + HH + l], hbl[b][l], a);
        }
        float m = a;
        m = fmaxf(m, __shfl_xor(m, 1, 8));
        m = fmaxf(m, __shfl_xor(m, 2, 8));
        m = fmaxf(m, __shfl_xor(m, 4, 8));
        float e = __expf(a - m);
        float s = e;
        s += __shfl_xor(s, 1, 8);
        s += __shfl_xor(s, 2, 8);
        s += __shfl_xor(s, 4, 8);
        out[(size_t)(b0 + b) * NCLS + n] = e / s;
    }
}

extern "C" void kernel_launch(void* const* d_in, const int* in_sizes, int n_in,
                              void* d_out, int out_size, void* d_ws, size_t ws_size,
                              hipStream_t stream) {
    const float* x     = (const float*)d_in[0];
    const float* Wih_f = (const float*)d_in[1];
    const float* Whh_f = (const float*)d_in[2];
    const float* bih_f = (const float*)d_in[3];
    const float* bhh_f = (const float*)d_in[4];
    const float* Wih_b = (const float*)d_in[5];
    // d_in[6] = Whh_b: unused — backward dir contributes only its first step (h0=0)
    const float* bih_b = (const float*)d_in[7];
    const float* bhh_b = (const float*)d_in[8];
    const float* fcW   = (const float*)d_in[9];
    const float* fcb   = (const float*)d_in[10];
    float* out = (float*)d_out;

    float* hf = (float*)d_ws;                                  // 512 KB
    const size_t XP_OFF  = 1u << 20;                           // 1 MB align
    const size_t XP_SIZE = (size_t)2048 * TT * G4 * 4;         // 512 MB
    if (ws_size >= XP_OFF + XP_SIZE) {
        float* xp = (float*)((char*)d_ws + XP_OFF);
        hipLaunchKernelGGL(xp_gemm, dim3((2048 * TT) / RPB), dim3(256), 0, stream,
                           x, Wih_f, bih_f, bhh_f, xp);
        hipLaunchKernelGGL(lstm_scan_xp, dim3(2048 / BT2), dim3(256), 0, stream,
                           xp, Whh_f, hf);
    } else {
        hipLaunchKernelGGL(lstm_fwd_scan, dim3(2048 / BT), dim3(256), 0, stream,
                           x, Wih_f, Whh_f, bih_f, bhh_f, hf);
    }
    hipLaunchKernelGGL(lstm_bwd_fc, dim3(2048 / B2), dim3(256), 0, stream,
                       x, Wih_b, bih_b, bhh_b, fcW, fcb, hf, out);
}